// Round 2
// baseline (621.376 us; speedup 1.0000x reference)
//
#include <hip/hip_runtime.h>
#include <hip/hip_bf16.h>
#include <math.h>

#define N 4096
#define DIN 512
#define DOUT 256
#define JS 8          // j-splits for the attention GEMM
#define JCH (N / JS)  // 512 j per block

typedef short bf16x8 __attribute__((ext_vector_type(8)));
typedef float f32x4 __attribute__((ext_vector_type(4)));

static __device__ __forceinline__ unsigned short f2bf(float x) {
  __hip_bfloat16 b = __float2bfloat16(x);
  return __builtin_bit_cast(unsigned short, b);
}

// ---------------- K1: p[i] = sum_k eta^k sum_o W[k,i,o]*d0[o], q likewise with d1 (f64) ----
__global__ __launch_bounds__(256) void k_pq(const float* __restrict__ W,
                                            const float* __restrict__ disc,
                                            double* __restrict__ p, double* __restrict__ q) {
  __shared__ double lds[8];
  int i = blockIdx.x;   // 0..511
  int t = threadIdx.x;  // 0..255 = o
  double accp = 0.0, accq = 0.0;
  const double wts[3] = {1.0, 0.5, 0.25};
#pragma unroll
  for (int k = 0; k < 3; ++k) {
    double w = (double)W[((size_t)(k * DIN + i)) * DOUT + t];
    accp += wts[k] * w * (double)disc[t];
    accq += wts[k] * w * (double)disc[DOUT + t];
  }
  for (int off = 32; off; off >>= 1) { accp += __shfl_down(accp, off); accq += __shfl_down(accq, off); }
  int l = t & 63, w_ = t >> 6;
  if (l == 0) { lds[w_] = accp; lds[4 + w_] = accq; }
  __syncthreads();
  if (t == 0) {
    p[i] = lds[0] + lds[1] + lds[2] + lds[3];
    q[i] = lds[4] + lds[5] + lds[6] + lds[7];
  }
}

// ---------------- K2: u[n] = sum_i h[n,i]*p[i], v[n] = sum_i h[n,i]*q[i]  (f64) -----------
__global__ __launch_bounds__(256) void k_uv(const float* __restrict__ h,
                                            const double* __restrict__ p, const double* __restrict__ q,
                                            double* __restrict__ u, double* __restrict__ v) {
  __shared__ double lds[8];
  int n = blockIdx.x, t = threadIdx.x;
  double su = 0.0, sv = 0.0;
#pragma unroll
  for (int i = t; i < DIN; i += 256) {
    double hv = (double)h[(size_t)n * DIN + i];
    su += hv * p[i];
    sv += hv * q[i];
  }
  for (int off = 32; off; off >>= 1) { su += __shfl_down(su, off); sv += __shfl_down(sv, off); }
  int l = t & 63, w_ = t >> 6;
  if (l == 0) { lds[w_] = su; lds[4 + w_] = sv; }
  __syncthreads();
  if (t == 0) {
    u[n] = lds[0] + lds[1] + lds[2] + lds[3];
    v[n] = lds[4] + lds[5] + lds[6] + lds[7];
  }
}

// ---------------- K3: denom = max(|min u + min v|, max u + max v); scal[0]=1/denom --------
__global__ __launch_bounds__(1024) void k_denom(const double* __restrict__ u,
                                                const double* __restrict__ v,
                                                double* __restrict__ scal) {
  __shared__ double lds[64];
  int t = threadIdx.x;
  double mnu = 1e300, mxu = -1e300, mnv = 1e300, mxv = -1e300;
#pragma unroll
  for (int k = 0; k < 4; ++k) {
    double uu = u[t + k * 1024], vv = v[t + k * 1024];
    mnu = fmin(mnu, uu); mxu = fmax(mxu, uu);
    mnv = fmin(mnv, vv); mxv = fmax(mxv, vv);
  }
  for (int off = 32; off; off >>= 1) {
    mnu = fmin(mnu, __shfl_down(mnu, off)); mxu = fmax(mxu, __shfl_down(mxu, off));
    mnv = fmin(mnv, __shfl_down(mnv, off)); mxv = fmax(mxv, __shfl_down(mxv, off));
  }
  int l = t & 63, w_ = t >> 6;  // 16 waves
  if (l == 0) { lds[w_] = mnu; lds[16 + w_] = mxu; lds[32 + w_] = mnv; lds[48 + w_] = mxv; }
  __syncthreads();
  if (t == 0) {
    double a = 1e300, b = -1e300, c = 1e300, d = -1e300;
    for (int k = 0; k < 16; ++k) {
      a = fmin(a, lds[k]); b = fmax(b, lds[16 + k]);
      c = fmin(c, lds[32 + k]); d = fmax(d, lds[48 + k]);
    }
    double mn = a + c, mx = b + d;
    double denom = fmax(fabs(mn), mx);
    scal[0] = 1.0 / denom;
  }
}

// ---------------- K4: dn + km planes (the big memory kernel) ------------------------------
__global__ __launch_bounds__(256) void k_dnkm(const int* __restrict__ kmask,
                                              const double* __restrict__ u, const double* __restrict__ v,
                                              const double* __restrict__ scal, const float* __restrict__ lamda,
                                              float* __restrict__ dn, float* __restrict__ kmout) {
  const size_t NN = (size_t)N * N;
  const int* k0 = kmask; const int* k1 = kmask + NN; const int* k2 = kmask + 2 * NN;
  float* km0 = kmout; float* km1 = kmout + NN; float* km2 = kmout + 2 * NN;
  const size_t total4 = NN / 4;
  double inv = scal[0];
  double lam = (double)lamda[0];
  for (size_t idx = (size_t)blockIdx.x * 256 + threadIdx.x; idx < total4;
       idx += (size_t)gridDim.x * 256) {
    int i = (int)(idx >> 10);        // N/4 = 1024 vec4s per row
    int j = (int)(idx & 1023) << 2;
    size_t base = (size_t)i * N + j;
    double ui = u[i];
    double2 va = *(const double2*)(v + j);
    double2 vb = *(const double2*)(v + j + 2);
    double vv[4] = {va.x, va.y, vb.x, vb.y};
    int4 m0 = *(const int4*)(k0 + base);
    int4 m1 = *(const int4*)(k1 + base);
    int4 m2 = *(const int4*)(k2 + base);
    float4 odn, o0, o1, o2;
#pragma unroll
    for (int c = 0; c < 4; ++c) {
      double dnv = (ui + vv[c]) * inv;
      bool pos = dnv > lam, neg = dnv < -lam;
      float dnf = (pos || neg) ? 0.0f : (float)dnv;
      int mk0 = (&m0.x)[c], mk1 = (&m1.x)[c], mk2 = (&m2.x)[c];
      int p0 = pos ? mk0 : 0;
      int p1 = pos ? mk1 : 0;
      int n0 = neg ? mk1 : 0;
      int n1 = neg ? mk2 : 0;
      (&odn.x)[c] = dnf;
      (&o0.x)[c] = (float)(mk0 - p0 - n0);
      (&o1.x)[c] = (float)(mk1 + p0 - p1 + n0 - n1);
      (&o2.x)[c] = (float)(mk2 + p1 + n1);
    }
    *(float4*)(dn + base) = odn;
    *(float4*)(km0 + base) = o0;
    *(float4*)(km1 + base) = o1;
    *(float4*)(km2 + base) = o2;
  }
}

// ---------------- K5: Wh0 = h @ W0 (f32 tiled GEMM), also emits bf16 Wh0^T ----------------
__global__ __launch_bounds__(256) void k_wh0(const float* __restrict__ h, const float* __restrict__ W,
                                             float* __restrict__ Wh0, unsigned short* __restrict__ Wh0T) {
  __shared__ float As[64][20];  // [m][k]
  __shared__ float Bs[16][72];  // [k][n]
  int t = threadIdx.x;
  int i0 = blockIdx.x * 64, o0 = blockIdx.y * 64;
  int tx = t & 15, ty = t >> 4;
  float acc[4][4] = {};
  int am = t >> 2, ak = (t & 3) * 4;   // A staging role
  int bk = t >> 4, bn = (t & 15) * 4;  // B staging role
  for (int kb = 0; kb < DIN; kb += 16) {
    float4 av = *(const float4*)(h + (size_t)(i0 + am) * DIN + kb + ak);
    float4 bv = *(const float4*)(W + (size_t)(kb + bk) * DOUT + o0 + bn);
    *(float4*)&As[am][ak] = av;
    *(float4*)&Bs[bk][bn] = bv;
    __syncthreads();
#pragma unroll
    for (int kk = 0; kk < 16; ++kk) {
      float a0 = As[ty * 4 + 0][kk], a1 = As[ty * 4 + 1][kk];
      float a2 = As[ty * 4 + 2][kk], a3 = As[ty * 4 + 3][kk];
      float4 b = *(const float4*)&Bs[kk][tx * 4];
      acc[0][0] += a0 * b.x; acc[0][1] += a0 * b.y; acc[0][2] += a0 * b.z; acc[0][3] += a0 * b.w;
      acc[1][0] += a1 * b.x; acc[1][1] += a1 * b.y; acc[1][2] += a1 * b.z; acc[1][3] += a1 * b.w;
      acc[2][0] += a2 * b.x; acc[2][1] += a2 * b.y; acc[2][2] += a2 * b.z; acc[2][3] += a2 * b.w;
      acc[3][0] += a3 * b.x; acc[3][1] += a3 * b.y; acc[3][2] += a3 * b.z; acc[3][3] += a3 * b.w;
    }
    __syncthreads();
  }
#pragma unroll
  for (int r = 0; r < 4; ++r) {
    int n = i0 + ty * 4 + r;
    float4 vo = {acc[r][0], acc[r][1], acc[r][2], acc[r][3]};
    *(float4*)(Wh0 + (size_t)n * DOUT + o0 + tx * 4) = vo;
#pragma unroll
    for (int c = 0; c < 4; ++c) {
      Wh0T[(size_t)(o0 + tx * 4 + c) * N + n] = f2bf(acc[r][c]);
    }
  }
}

// ---------------- K6: s1[n] = Wh0[n,:]·a00, s2[n] = Wh0[n,:]·a01 --------------------------
__global__ __launch_bounds__(256) void k_s1s2(const float* __restrict__ Wh0, const float* __restrict__ a,
                                              float* __restrict__ s1, float* __restrict__ s2) {
  __shared__ float lds[8];
  int i = blockIdx.x, t = threadIdx.x;
  float val = Wh0[(size_t)i * DOUT + t];
  float v1 = val * a[t];
  float v2 = val * a[DOUT + t];
  for (int off = 32; off; off >>= 1) { v1 += __shfl_down(v1, off); v2 += __shfl_down(v2, off); }
  int l = t & 63, w_ = t >> 6;
  if (l == 0) { lds[w_] = v1; lds[4 + w_] = v2; }
  __syncthreads();
  if (t == 0) {
    s1[i] = lds[0] + lds[1] + lds[2] + lds[3];
    s2[i] = lds[4] + lds[5] + lds[6] + lds[7];
  }
}

// ---------------- K7: per-row masked softmax stats: m, 1/Z, all-masked flag ---------------
__global__ __launch_bounds__(256) void k_rowstats(const int* __restrict__ k0,
                                                  const float* __restrict__ s1, const float* __restrict__ s2,
                                                  float* __restrict__ mrow, float* __restrict__ zinv,
                                                  int* __restrict__ flag) {
  __shared__ float earr[N];   // 16KB
  __shared__ float redf[4];
  __shared__ int redi[4];
  __shared__ float bm; __shared__ int bc;
  int i = blockIdx.x, t = threadIdx.x;
  float s1i = s1[i];
  float lmax = -1e30f; int lcnt = 0;
  for (int j = t; j < N; j += 256) {
    int mk = k0[(size_t)i * N + j];
    float sv = s1i + s2[j];
    float e = sv >= 0.0f ? sv : 0.2f * sv;
    bool um = mk > 0;
    earr[j] = um ? e : -1e30f;
    if (um) { lmax = fmaxf(lmax, e); lcnt++; }
  }
  for (int off = 32; off; off >>= 1) { lmax = fmaxf(lmax, __shfl_down(lmax, off)); lcnt += __shfl_down(lcnt, off); }
  int l = t & 63, w_ = t >> 6;
  if (l == 0) { redf[w_] = lmax; redi[w_] = lcnt; }
  __syncthreads();
  if (t == 0) {
    bm = fmaxf(fmaxf(redf[0], redf[1]), fmaxf(redf[2], redf[3]));
    bc = redi[0] + redi[1] + redi[2] + redi[3];
  }
  __syncthreads();
  float m = bm; int c = bc;
  float lsum = 0.0f;
  if (c > 0) {
    for (int j = t; j < N; j += 256) {
      float e = earr[j];
      if (e > -1e29f) lsum += expf(e - m);
    }
  }
  for (int off = 32; off; off >>= 1) lsum += __shfl_down(lsum, off);
  if (l == 0) redf[w_] = lsum;
  __syncthreads();
  if (t == 0) {
    float Z = redf[0] + redf[1] + redf[2] + redf[3];
    if (c == 0) { mrow[i] = 0.0f; zinv[i] = 1.0f / (float)N; flag[i] = 1; }
    else        { mrow[i] = m;    zinv[i] = 1.0f / Z;        flag[i] = 0; }
  }
}

// ---------------- K8: j-split attention GEMM, P in registers, no barriers -----------------
// Grid (N/16, JS). Block = 4 waves; wave w owns o-range [w*64, w*64+64).
// Lane l: A-row = l&15, k-group = l>>4. Computes P[row][j..j+7] in regs (8 expf),
// feeds mfma_f32_16x16x32_bf16 against Wh0T fragments. Partial O into Opart[by].
__global__ __launch_bounds__(256) void k_attn2(const int* __restrict__ k0,
                                               const float* __restrict__ s1, const float* __restrict__ s2,
                                               const float* __restrict__ mrow, const int* __restrict__ flag,
                                               const unsigned short* __restrict__ Wh0T,
                                               float* __restrict__ Opart) {
  int t = threadIdx.x;
  int i0 = blockIdx.x * 16;
  int w = t >> 6, l = t & 63;
  int o0 = w * 64;
  int row = l & 15;   // A fragment row / B fragment col
  int kg = l >> 4;    // k-slot group (0..3) -> k = 8*kg..8*kg+7
  int irow = i0 + row;
  float s1r = s1[irow], mr = mrow[irow];
  int fl = flag[irow];
  f32x4 acc0 = {0,0,0,0}, acc1 = {0,0,0,0}, acc2 = {0,0,0,0}, acc3 = {0,0,0,0};
  const unsigned short* bbase = Wh0T + ((size_t)(o0 + row) * N + 8 * kg);
  const int* mbase = k0 + (size_t)irow * N + 8 * kg;
  const float* sbase = s2 + 8 * kg;
  int jbeg = blockIdx.y * JCH;
  for (int j0 = jbeg; j0 < jbeg + JCH; j0 += 32) {
    int4 ma = *(const int4*)(mbase + j0);
    int4 mb = *(const int4*)(mbase + j0 + 4);
    float4 sa = *(const float4*)(sbase + j0);
    float4 sb = *(const float4*)(sbase + j0 + 4);
    float pv[8];
#pragma unroll
    for (int c = 0; c < 4; ++c) {
      float sv = s1r + (&sa.x)[c];
      float e = sv >= 0.0f ? sv : 0.2f * sv;
      pv[c] = fl ? 1.0f : ((&ma.x)[c] > 0 ? expf(e - mr) : 0.0f);
    }
#pragma unroll
    for (int c = 0; c < 4; ++c) {
      float sv = s1r + (&sb.x)[c];
      float e = sv >= 0.0f ? sv : 0.2f * sv;
      pv[4 + c] = fl ? 1.0f : ((&mb.x)[c] > 0 ? expf(e - mr) : 0.0f);
    }
    bf16x8 af;
#pragma unroll
    for (int c = 0; c < 8; ++c) af[c] = (short)f2bf(pv[c]);
    bf16x8 b0 = *(const bf16x8*)(bbase + j0);
    bf16x8 b1 = *(const bf16x8*)(bbase + 16 * N + j0);
    bf16x8 b2 = *(const bf16x8*)(bbase + 32 * N + j0);
    bf16x8 b3 = *(const bf16x8*)(bbase + 48 * N + j0);
    acc0 = __builtin_amdgcn_mfma_f32_16x16x32_bf16(af, b0, acc0, 0, 0, 0);
    acc1 = __builtin_amdgcn_mfma_f32_16x16x32_bf16(af, b1, acc1, 0, 0, 0);
    acc2 = __builtin_amdgcn_mfma_f32_16x16x32_bf16(af, b2, acc2, 0, 0, 0);
    acc3 = __builtin_amdgcn_mfma_f32_16x16x32_bf16(af, b3, acc3, 0, 0, 0);
  }
  // epilogue: C[row=(l>>4)*4+reg][col=l&15]
  float* op = Opart + (size_t)blockIdx.y * N * DOUT;
  int col = l & 15, rw = (l >> 4) * 4;
  f32x4 accs[4] = {acc0, acc1, acc2, acc3};
#pragma unroll
  for (int reg = 0; reg < 4; ++reg) {
    int i = i0 + rw + reg;
#pragma unroll
    for (int os = 0; os < 4; ++os) {
      op[(size_t)i * DOUT + o0 + os * 16 + col] = accs[os][reg];
    }
  }
}

// ---------------- K9: reduce JS partials, apply zinv, skip term, ELU ----------------------
__global__ __launch_bounds__(256) void k_ored(const float* __restrict__ Opart,
                                              const float* __restrict__ Wh0,
                                              const float* __restrict__ zinv,
                                              float* __restrict__ out) {
  int i = blockIdx.x, t = threadIdx.x;
  size_t idx = (size_t)i * DOUT + t;
  float s = 0.0f;
#pragma unroll
  for (int by = 0; by < JS; ++by) s += Opart[(size_t)by * N * DOUT + idx];
  float val = 0.9f * s * zinv[i] + 0.1f * Wh0[idx];
  out[idx] = val > 0.0f ? val : expm1f(val);
}

extern "C" void kernel_launch(void* const* d_in, const int* in_sizes, int n_in,
                              void* d_out, int out_size, void* d_ws, size_t ws_size,
                              hipStream_t stream) {
  const float* h     = (const float*)d_in[0];
  const float* W     = (const float*)d_in[1];
  const float* a     = (const float*)d_in[2];
  const float* disc  = (const float*)d_in[3];
  const int*   kmask = (const int*)d_in[4];
  const float* lamda = (const float*)d_in[5];

  float* out = (float*)d_out;                    // [N, DOUT]
  float* dn  = out + (size_t)N * DOUT;           // [N, N]
  float* km  = dn + (size_t)N * N;               // [3, N, N]

  char* ws = (char*)d_ws;
  double* p    = (double*)ws;                          // 4KB
  double* q    = (double*)(ws + 4096);                 // 4KB
  double* u    = (double*)(ws + 8192);                 // 32KB
  double* v    = (double*)(ws + 8192 + 32768);         // 32KB
  double* scal = (double*)(ws + 8192 + 65536);         // 8B (+pad)
  char* ws2 = ws + 8192 + 65536 + 256;
  float* s1   = (float*)ws2;                           // 16KB
  float* s2   = (float*)(ws2 + 16384);                 // 16KB
  float* mrow = (float*)(ws2 + 32768);                 // 16KB
  float* zin  = (float*)(ws2 + 49152);                 // 16KB
  int*   flag = (int*)(ws2 + 65536);                   // 16KB
  float* Wh0  = (float*)(ws2 + 65536 + 16384);         // 4MB
  unsigned short* Wh0T = (unsigned short*)(ws2 + 65536 + 16384 + (size_t)N * DOUT * 4);  // 2MB
  float* Opart = (float*)(ws2 + 65536 + 16384 + (size_t)N * DOUT * 4 + (size_t)N * DOUT * 2);  // 32MB

  k_pq<<<DIN, 256, 0, stream>>>(W, disc, p, q);
  k_uv<<<N, 256, 0, stream>>>(h, p, q, u, v);
  k_denom<<<1, 1024, 0, stream>>>(u, v, scal);
  k_dnkm<<<4096, 256, 0, stream>>>(kmask, u, v, scal, lamda, dn, km);
  k_wh0<<<dim3(64, 4), 256, 0, stream>>>(h, W, Wh0, Wh0T);
  k_s1s2<<<N, 256, 0, stream>>>(Wh0, a, s1, s2);
  k_rowstats<<<N, 256, 0, stream>>>(kmask, s1, s2, mrow, zin, flag);
  k_attn2<<<dim3(N / 16, JS), 256, 0, stream>>>(kmask, s1, s2, mrow, flag, Wh0T, Opart);
  k_ored<<<N, 256, 0, stream>>>(Opart, Wh0, zin, out);
}

// Round 4
// 603.544 us; speedup vs baseline: 1.0295x; 1.0295x over previous
//
#include <hip/hip_runtime.h>
#include <hip/hip_bf16.h>
#include <math.h>

#define N 4096
#define DIN 512
#define DOUT 256
#define JS 8          // j-splits for the attention GEMM
#define JCH (N / JS)  // 512 j per split

typedef short bf16x8 __attribute__((ext_vector_type(8)));
typedef float f32x4 __attribute__((ext_vector_type(4)));
typedef int i32x4 __attribute__((ext_vector_type(4)));

static __device__ __forceinline__ unsigned short f2bf(float x) {
  __hip_bfloat16 b = __float2bfloat16(x);
  return __builtin_bit_cast(unsigned short, b);
}

// order-preserving float<->uint for atomicMax on possibly-negative floats
static __device__ __forceinline__ unsigned int f2ord(float f) {
  unsigned int b = __float_as_uint(f);
  return (b & 0x80000000u) ? ~b : (b | 0x80000000u);
}
static __device__ __forceinline__ float ord2f(unsigned int u) {
  unsigned int b = (u & 0x80000000u) ? (u ^ 0x80000000u) : ~u;
  return __uint_as_float(b);
}

// ---------------- K1: p[i] = sum_k eta^k sum_o W[k,i,o]*d0[o], q likewise (f64) ----------
// also zero-inits the s2-max atomic word (ord-encoded; 0 == -inf sentinel)
__global__ __launch_bounds__(256) void k_pq(const float* __restrict__ W,
                                            const float* __restrict__ disc,
                                            double* __restrict__ p, double* __restrict__ q,
                                            unsigned int* __restrict__ smaxw) {
  if (blockIdx.x == 0 && threadIdx.x == 0) smaxw[0] = 0u;
  __shared__ double lds[8];
  int i = blockIdx.x;   // 0..511
  int t = threadIdx.x;  // 0..255 = o
  double accp = 0.0, accq = 0.0;
  const double wts[3] = {1.0, 0.5, 0.25};
#pragma unroll
  for (int k = 0; k < 3; ++k) {
    double w = (double)W[((size_t)(k * DIN + i)) * DOUT + t];
    accp += wts[k] * w * (double)disc[t];
    accq += wts[k] * w * (double)disc[DOUT + t];
  }
  for (int off = 32; off; off >>= 1) { accp += __shfl_down(accp, off); accq += __shfl_down(accq, off); }
  int l = t & 63, w_ = t >> 6;
  if (l == 0) { lds[w_] = accp; lds[4 + w_] = accq; }
  __syncthreads();
  if (t == 0) {
    p[i] = lds[0] + lds[1] + lds[2] + lds[3];
    q[i] = lds[4] + lds[5] + lds[6] + lds[7];
  }
}

// ---------------- K2: u[n] = sum_i h[n,i]*p[i], v[n] likewise (f64) -----------------------
__global__ __launch_bounds__(256) void k_uv(const float* __restrict__ h,
                                            const double* __restrict__ p, const double* __restrict__ q,
                                            double* __restrict__ u, double* __restrict__ v) {
  __shared__ double lds[8];
  int n = blockIdx.x, t = threadIdx.x;
  double su = 0.0, sv = 0.0;
#pragma unroll
  for (int i = t; i < DIN; i += 256) {
    double hv = (double)h[(size_t)n * DIN + i];
    su += hv * p[i];
    sv += hv * q[i];
  }
  for (int off = 32; off; off >>= 1) { su += __shfl_down(su, off); sv += __shfl_down(sv, off); }
  int l = t & 63, w_ = t >> 6;
  if (l == 0) { lds[w_] = su; lds[4 + w_] = sv; }
  __syncthreads();
  if (t == 0) {
    u[n] = lds[0] + lds[1] + lds[2] + lds[3];
    v[n] = lds[4] + lds[5] + lds[6] + lds[7];
  }
}

// ---------------- K3: scal[0] = 1 / max(|min u+min v|, max u+max v) -----------------------
__global__ __launch_bounds__(1024) void k_denom(const double* __restrict__ u,
                                                const double* __restrict__ v,
                                                double* __restrict__ scal) {
  __shared__ double lds[64];
  int t = threadIdx.x;
  double mnu = 1e300, mxu = -1e300, mnv = 1e300, mxv = -1e300;
#pragma unroll
  for (int k = 0; k < 4; ++k) {
    double uu = u[t + k * 1024], vv = v[t + k * 1024];
    mnu = fmin(mnu, uu); mxu = fmax(mxu, uu);
    mnv = fmin(mnv, vv); mxv = fmax(mxv, vv);
  }
  for (int off = 32; off; off >>= 1) {
    mnu = fmin(mnu, __shfl_down(mnu, off)); mxu = fmax(mxu, __shfl_down(mxu, off));
    mnv = fmin(mnv, __shfl_down(mnv, off)); mxv = fmax(mxv, __shfl_down(mxv, off));
  }
  int l = t & 63, w_ = t >> 6;  // 16 waves
  if (l == 0) { lds[w_] = mnu; lds[16 + w_] = mxu; lds[32 + w_] = mnv; lds[48 + w_] = mxv; }
  __syncthreads();
  if (t == 0) {
    double a = 1e300, b = -1e300, c = 1e300, d = -1e300;
    for (int k = 0; k < 16; ++k) {
      a = fmin(a, lds[k]); b = fmax(b, lds[16 + k]);
      c = fmin(c, lds[32 + k]); d = fmax(d, lds[48 + k]);
    }
    double mn = a + c, mx = b + d;
    scal[0] = 1.0 / fmax(fabs(mn), mx);
  }
}

// ---------------- K4: dn + km planes (big streaming kernel, nontemporal) ------------------
__global__ __launch_bounds__(256) void k_dnkm(const int* __restrict__ kmask,
                                              const double* __restrict__ u, const double* __restrict__ v,
                                              const double* __restrict__ scal, const float* __restrict__ lamda,
                                              float* __restrict__ dn, float* __restrict__ kmout) {
  const size_t NN = (size_t)N * N;
  const int* k0 = kmask; const int* k1 = kmask + NN; const int* k2 = kmask + 2 * NN;
  float* km0 = kmout; float* km1 = kmout + NN; float* km2 = kmout + 2 * NN;
  const size_t total4 = NN / 4;
  double inv = scal[0];
  double lam = (double)lamda[0];
  for (size_t idx = (size_t)blockIdx.x * 256 + threadIdx.x; idx < total4;
       idx += (size_t)gridDim.x * 256) {
    int i = (int)(idx >> 10);
    int j = (int)(idx & 1023) << 2;
    size_t base = (size_t)i * N + j;
    double ui = u[i];
    double2 va = *(const double2*)(v + j);
    double2 vb = *(const double2*)(v + j + 2);
    double vv[4] = {va.x, va.y, vb.x, vb.y};
    i32x4 m0 = __builtin_nontemporal_load((const i32x4*)(k0 + base));
    i32x4 m1 = __builtin_nontemporal_load((const i32x4*)(k1 + base));
    i32x4 m2 = __builtin_nontemporal_load((const i32x4*)(k2 + base));
    f32x4 odn, o0, o1, o2;
#pragma unroll
    for (int c = 0; c < 4; ++c) {
      double dnv = (ui + vv[c]) * inv;
      bool pos = dnv > lam, neg = dnv < -lam;
      float dnf = (pos || neg) ? 0.0f : (float)dnv;
      int mk0 = m0[c], mk1 = m1[c], mk2 = m2[c];
      int p0 = pos ? mk0 : 0;
      int p1 = pos ? mk1 : 0;
      int n0 = neg ? mk1 : 0;
      int n1 = neg ? mk2 : 0;
      odn[c] = dnf;
      o0[c] = (float)(mk0 - p0 - n0);
      o1[c] = (float)(mk1 + p0 - p1 + n0 - n1);
      o2[c] = (float)(mk2 + p1 + n1);
    }
    __builtin_nontemporal_store(odn, (f32x4*)(dn + base));
    __builtin_nontemporal_store(o0, (f32x4*)(km0 + base));
    __builtin_nontemporal_store(o1, (f32x4*)(km1 + base));
    __builtin_nontemporal_store(o2, (f32x4*)(km2 + base));
  }
}

// ---------------- K5: Wh0 = h @ W0 (f32, 32x64 tiles, 2 blocks/CU, reg double-buffer) -----
__global__ __launch_bounds__(256) void k_wh0(const float* __restrict__ h, const float* __restrict__ W,
                                             float* __restrict__ Wh0, unsigned short* __restrict__ Wh0T) {
  __shared__ float As[32][20];  // [m][k]
  __shared__ float Bs[16][72];  // [k][n]
  int t = threadIdx.x;
  int i0 = blockIdx.x * 32, o0 = blockIdx.y * 64;
  int tx = t & 15, ty = t >> 4;
  float acc[2][4] = {};
  int am = t >> 2, ak = (t & 3) * 4;   // A staging (t<128)
  int bk = t >> 4, bn = (t & 15) * 4;  // B staging
  float4 pa, pb;
  if (t < 128) pa = *(const float4*)(h + (size_t)(i0 + am) * DIN + ak);
  pb = *(const float4*)(W + (size_t)bk * DOUT + o0 + bn);
  for (int kb = 0; kb < DIN; kb += 16) {
    if (t < 128) *(float4*)&As[am][ak] = pa;
    *(float4*)&Bs[bk][bn] = pb;
    __syncthreads();
    if (kb + 16 < DIN) {
      if (t < 128) pa = *(const float4*)(h + (size_t)(i0 + am) * DIN + kb + 16 + ak);
      pb = *(const float4*)(W + (size_t)(kb + 16 + bk) * DOUT + o0 + bn);
    }
#pragma unroll
    for (int kk = 0; kk < 16; ++kk) {
      float a0 = As[ty * 2 + 0][kk], a1 = As[ty * 2 + 1][kk];
      float4 b = *(const float4*)&Bs[kk][tx * 4];
      acc[0][0] += a0 * b.x; acc[0][1] += a0 * b.y; acc[0][2] += a0 * b.z; acc[0][3] += a0 * b.w;
      acc[1][0] += a1 * b.x; acc[1][1] += a1 * b.y; acc[1][2] += a1 * b.z; acc[1][3] += a1 * b.w;
    }
    __syncthreads();
  }
#pragma unroll
  for (int r = 0; r < 2; ++r) {
    int n = i0 + ty * 2 + r;
    float4 vo = {acc[r][0], acc[r][1], acc[r][2], acc[r][3]};
    *(float4*)(Wh0 + (size_t)n * DOUT + o0 + tx * 4) = vo;
#pragma unroll
    for (int c = 0; c < 4; ++c) {
      Wh0T[(size_t)(o0 + tx * 4 + c) * N + n] = f2bf(acc[r][c]);
    }
  }
}

// ---------------- K6: s1[n], s2[n]; atomicMax of s2 into smaxw ---------------------------
__global__ __launch_bounds__(256) void k_s1s2(const float* __restrict__ Wh0, const float* __restrict__ a,
                                              float* __restrict__ s1, float* __restrict__ s2,
                                              unsigned int* __restrict__ smaxw) {
  __shared__ float lds[8];
  int i = blockIdx.x, t = threadIdx.x;
  float val = Wh0[(size_t)i * DOUT + t];
  float v1 = val * a[t];
  float v2 = val * a[DOUT + t];
  for (int off = 32; off; off >>= 1) { v1 += __shfl_down(v1, off); v2 += __shfl_down(v2, off); }
  int l = t & 63, w_ = t >> 6;
  if (l == 0) { lds[w_] = v1; lds[4 + w_] = v2; }
  __syncthreads();
  if (t == 0) {
    s1[i] = lds[0] + lds[1] + lds[2] + lds[3];
    float s2i = lds[4] + lds[5] + lds[6] + lds[7];
    s2[i] = s2i;
    atomicMax(smaxw, f2ord(s2i));
  }
}

// ---------------- K7: j-split attention GEMM, fixed-bound max, no barriers ----------------
// Grid (N/32, JS), 512 threads = 8 waves. Wave w: rows rbase=(w>>2)*16, o0=(w&3)*64.
// Lane l: row = l&15, k-slot group kg = l>>4. P computed in regs, Z accumulated per row.
__global__ __launch_bounds__(512) void k_attn2(const int* __restrict__ k0,
                                               const float* __restrict__ s1, const float* __restrict__ s2,
                                               const unsigned int* __restrict__ smaxw,
                                               const unsigned short* __restrict__ Wh0T,
                                               float* __restrict__ Opart, float* __restrict__ Zpart) {
  int t = threadIdx.x;
  int w = t >> 6, l = t & 63;
  int o0 = (w & 3) * 64;
  int rbase = blockIdx.x * 32 + (w >> 2) * 16;
  int row = l & 15;
  int kg = l >> 4;
  int irow = rbase + row;
  float s1r = s1[irow];
  float sm2 = ord2f(smaxw[0]);
  float mb = s1r + sm2;
  float mi = mb >= 0.0f ? mb : 0.2f * mb;   // upper bound of masked row max
  f32x4 acc0 = {0,0,0,0}, acc1 = {0,0,0,0}, acc2 = {0,0,0,0}, acc3 = {0,0,0,0};
  float zacc = 0.0f;
  const unsigned short* bbase = Wh0T + ((size_t)(o0 + row) * N + 8 * kg);
  const int* mbase = k0 + (size_t)irow * N + 8 * kg;
  const float* sbase = s2 + 8 * kg;
  int jbeg = blockIdx.y * JCH;
  for (int j0 = jbeg; j0 < jbeg + JCH; j0 += 32) {
    int4 ma = *(const int4*)(mbase + j0);
    int4 mb4 = *(const int4*)(mbase + j0 + 4);
    float4 sa = *(const float4*)(sbase + j0);
    float4 sb = *(const float4*)(sbase + j0 + 4);
    float pv[8];
#pragma unroll
    for (int c = 0; c < 4; ++c) {
      float sv = s1r + (&sa.x)[c];
      float e = sv >= 0.0f ? sv : 0.2f * sv;
      pv[c] = (&ma.x)[c] > 0 ? __expf(e - mi) : 0.0f;
    }
#pragma unroll
    for (int c = 0; c < 4; ++c) {
      float sv = s1r + (&sb.x)[c];
      float e = sv >= 0.0f ? sv : 0.2f * sv;
      pv[4 + c] = (&mb4.x)[c] > 0 ? __expf(e - mi) : 0.0f;
    }
    bf16x8 af;
#pragma unroll
    for (int c = 0; c < 8; ++c) af[c] = (short)f2bf(pv[c]);
    zacc += pv[0] + pv[1] + pv[2] + pv[3] + pv[4] + pv[5] + pv[6] + pv[7];
    bf16x8 b0 = *(const bf16x8*)(bbase + j0);
    bf16x8 b1 = *(const bf16x8*)(bbase + 16 * N + j0);
    bf16x8 b2 = *(const bf16x8*)(bbase + 32 * N + j0);
    bf16x8 b3 = *(const bf16x8*)(bbase + 48 * N + j0);
    acc0 = __builtin_amdgcn_mfma_f32_16x16x32_bf16(af, b0, acc0, 0, 0, 0);
    acc1 = __builtin_amdgcn_mfma_f32_16x16x32_bf16(af, b1, acc1, 0, 0, 0);
    acc2 = __builtin_amdgcn_mfma_f32_16x16x32_bf16(af, b2, acc2, 0, 0, 0);
    acc3 = __builtin_amdgcn_mfma_f32_16x16x32_bf16(af, b3, acc3, 0, 0, 0);
  }
  // Z: reduce over the 4 lanes sharing a row (kg groups)
  zacc += __shfl_xor(zacc, 16);
  zacc += __shfl_xor(zacc, 32);
  if ((w & 3) == 0 && l < 16) Zpart[(size_t)blockIdx.y * N + rbase + l] = zacc;
  // Opart epilogue: C[row=(l>>4)*4+reg][col=l&15]
  float* op = Opart + (size_t)blockIdx.y * N * DOUT;
  int col = l & 15, rw = (l >> 4) * 4;
  f32x4 accs[4] = {acc0, acc1, acc2, acc3};
#pragma unroll
  for (int reg = 0; reg < 4; ++reg) {
    int i = rbase + rw + reg;
#pragma unroll
    for (int os = 0; os < 4; ++os) {
      op[(size_t)i * DOUT + o0 + os * 16 + col] = accs[os][reg];
    }
  }
}

// ---------------- K8: reduce JS partials, normalize, skip term, ELU -----------------------
__global__ __launch_bounds__(256) void k_ored(const float* __restrict__ Opart,
                                              const float* __restrict__ Zpart,
                                              const float* __restrict__ Wh0,
                                              float* __restrict__ out) {
  int i = blockIdx.x, t = threadIdx.x;
  size_t idx = (size_t)i * DOUT + t;
  float s = 0.0f, z = 0.0f;
#pragma unroll
  for (int sp = 0; sp < JS; ++sp) {
    s += Opart[(size_t)sp * N * DOUT + idx];
    z += Zpart[(size_t)sp * N + i];
  }
  float val = 0.9f * (s / z) + 0.1f * Wh0[idx];
  out[idx] = val > 0.0f ? val : expm1f(val);
}

extern "C" void kernel_launch(void* const* d_in, const int* in_sizes, int n_in,
                              void* d_out, int out_size, void* d_ws, size_t ws_size,
                              hipStream_t stream) {
  const float* h     = (const float*)d_in[0];
  const float* W     = (const float*)d_in[1];
  const float* a     = (const float*)d_in[2];
  const float* disc  = (const float*)d_in[3];
  const int*   kmask = (const int*)d_in[4];
  const float* lamda = (const float*)d_in[5];

  float* out = (float*)d_out;                    // [N, DOUT]
  float* dn  = out + (size_t)N * DOUT;           // [N, N]
  float* km  = dn + (size_t)N * N;               // [3, N, N]

  char* ws = (char*)d_ws;
  double* p    = (double*)ws;                          // 4KB
  double* q    = (double*)(ws + 4096);                 // 4KB
  double* u    = (double*)(ws + 8192);                 // 32KB
  double* v    = (double*)(ws + 8192 + 32768);         // 32KB
  double* scal = (double*)(ws + 8192 + 65536);         // 8B (+pad to 256)
  char* ws2 = ws + 8192 + 65536 + 256;
  float* s1            = (float*)ws2;                          // 16KB
  float* s2            = (float*)(ws2 + 16384);                // 16KB
  unsigned int* smaxw  = (unsigned int*)(ws2 + 32768);         // 256B
  float* Zpart         = (float*)(ws2 + 33024);                // JS*N*4 = 128KB
  char* ws3 = ws2 + 33024 + (size_t)JS * N * 4;
  float* Wh0           = (float*)ws3;                          // 4MB
  unsigned short* Wh0T = (unsigned short*)(ws3 + (size_t)N * DOUT * 4);  // 2MB
  float* Opart         = (float*)(ws3 + (size_t)N * DOUT * 6);           // 32MB

  k_pq<<<DIN, 256, 0, stream>>>(W, disc, p, q, smaxw);
  k_uv<<<N, 256, 0, stream>>>(h, p, q, u, v);
  k_denom<<<1, 1024, 0, stream>>>(u, v, scal);
  k_dnkm<<<4096, 256, 0, stream>>>(kmask, u, v, scal, lamda, dn, km);
  k_wh0<<<dim3(N / 32, DOUT / 64), 256, 0, stream>>>(h, W, Wh0, Wh0T);
  k_s1s2<<<N, 256, 0, stream>>>(Wh0, a, s1, s2, smaxw);
  k_attn2<<<dim3(N / 32, JS), 512, 0, stream>>>(kmask, s1, s2, smaxw, Wh0T, Opart, Zpart);
  k_ored<<<N, 256, 0, stream>>>(Opart, Zpart, Wh0, out);
}

// Round 5
// 539.570 us; speedup vs baseline: 1.1516x; 1.1186x over previous
//
#include <hip/hip_runtime.h>
#include <hip/hip_bf16.h>
#include <math.h>

#define N 4096
#define DIN 512
#define DOUT 256
#define JS 8          // j-splits for the attention GEMM
#define JCH (N / JS)  // 512 j per split

typedef short bf16x8 __attribute__((ext_vector_type(8)));
typedef float f32x4 __attribute__((ext_vector_type(4)));
typedef int i32x4 __attribute__((ext_vector_type(4)));
typedef unsigned short u16x4 __attribute__((ext_vector_type(4)));

static __device__ __forceinline__ unsigned short f2bf(float x) {
  __hip_bfloat16 b = __float2bfloat16(x);
  return __builtin_bit_cast(unsigned short, b);
}

// ---------------- K1: p[i], q[i] (f64 rank-1 collapse of dischange); zero s1/s2 ----------
__global__ __launch_bounds__(256) void k_pq(const float* __restrict__ W,
                                            const float* __restrict__ disc,
                                            double* __restrict__ p, double* __restrict__ q,
                                            float* __restrict__ s1, float* __restrict__ s2) {
  int i = blockIdx.x;   // 0..511
  int t = threadIdx.x;  // 0..255 = o
  if (i < 16) s1[i * 256 + t] = 0.0f;
  else if (i < 32) s2[(i - 16) * 256 + t] = 0.0f;
  __shared__ double lds[8];
  double accp = 0.0, accq = 0.0;
  const double wts[3] = {1.0, 0.5, 0.25};
#pragma unroll
  for (int k = 0; k < 3; ++k) {
    double w = (double)W[((size_t)(k * DIN + i)) * DOUT + t];
    accp += wts[k] * w * (double)disc[t];
    accq += wts[k] * w * (double)disc[DOUT + t];
  }
  for (int off = 32; off; off >>= 1) { accp += __shfl_down(accp, off); accq += __shfl_down(accq, off); }
  int l = t & 63, w_ = t >> 6;
  if (l == 0) { lds[w_] = accp; lds[4 + w_] = accq; }
  __syncthreads();
  if (t == 0) {
    p[i] = lds[0] + lds[1] + lds[2] + lds[3];
    q[i] = lds[4] + lds[5] + lds[6] + lds[7];
  }
}

// ---------------- K2: u[n] = h[n,:]·p, v[n] = h[n,:]·q (f64) ------------------------------
__global__ __launch_bounds__(256) void k_uv(const float* __restrict__ h,
                                            const double* __restrict__ p, const double* __restrict__ q,
                                            double* __restrict__ u, double* __restrict__ v) {
  __shared__ double lds[8];
  int n = blockIdx.x, t = threadIdx.x;
  double su = 0.0, sv = 0.0;
#pragma unroll
  for (int i = t; i < DIN; i += 256) {
    double hv = (double)h[(size_t)n * DIN + i];
    su += hv * p[i];
    sv += hv * q[i];
  }
  for (int off = 32; off; off >>= 1) { su += __shfl_down(su, off); sv += __shfl_down(sv, off); }
  int l = t & 63, w_ = t >> 6;
  if (l == 0) { lds[w_] = su; lds[4 + w_] = sv; }
  __syncthreads();
  if (t == 0) {
    u[n] = lds[0] + lds[1] + lds[2] + lds[3];
    v[n] = lds[4] + lds[5] + lds[6] + lds[7];
  }
}

// ---------------- K3: Wh0 = h @ W0 (f32) + Wh0T bf16 + s1/s2 atomic partials --------------
__global__ __launch_bounds__(256) void k_wh0(const float* __restrict__ h, const float* __restrict__ W,
                                             const float* __restrict__ a,
                                             float* __restrict__ Wh0, unsigned short* __restrict__ Wh0T,
                                             float* __restrict__ s1, float* __restrict__ s2) {
  __shared__ float As[32][20];  // [m][k]
  __shared__ float Bs[16][72];  // [k][n]
  int t = threadIdx.x;
  int i0 = blockIdx.x * 32, o0 = blockIdx.y * 64;
  int tx = t & 15, ty = t >> 4;
  float acc[2][4] = {};
  int am = t >> 2, ak = (t & 3) * 4;   // A staging (t<128)
  int bk = t >> 4, bn = (t & 15) * 4;  // B staging
  float4 pa, pb;
  if (t < 128) pa = *(const float4*)(h + (size_t)(i0 + am) * DIN + ak);
  pb = *(const float4*)(W + (size_t)bk * DOUT + o0 + bn);
  for (int kb = 0; kb < DIN; kb += 16) {
    if (t < 128) *(float4*)&As[am][ak] = pa;
    *(float4*)&Bs[bk][bn] = pb;
    __syncthreads();
    if (kb + 16 < DIN) {
      if (t < 128) pa = *(const float4*)(h + (size_t)(i0 + am) * DIN + kb + 16 + ak);
      pb = *(const float4*)(W + (size_t)(kb + 16 + bk) * DOUT + o0 + bn);
    }
#pragma unroll
    for (int kk = 0; kk < 16; ++kk) {
      float a0 = As[ty * 2 + 0][kk], a1 = As[ty * 2 + 1][kk];
      float4 b = *(const float4*)&Bs[kk][tx * 4];
      acc[0][0] += a0 * b.x; acc[0][1] += a0 * b.y; acc[0][2] += a0 * b.z; acc[0][3] += a0 * b.w;
      acc[1][0] += a1 * b.x; acc[1][1] += a1 * b.y; acc[1][2] += a1 * b.z; acc[1][3] += a1 * b.w;
    }
    __syncthreads();
  }
  float4 a1v = *(const float4*)(a + o0 + tx * 4);
  float4 a2v = *(const float4*)(a + DOUT + o0 + tx * 4);
#pragma unroll
  for (int r = 0; r < 2; ++r) {
    int n = i0 + ty * 2 + r;
    float4 vo = {acc[r][0], acc[r][1], acc[r][2], acc[r][3]};
    *(float4*)(Wh0 + (size_t)n * DOUT + o0 + tx * 4) = vo;
#pragma unroll
    for (int c = 0; c < 4; ++c) {
      Wh0T[(size_t)(o0 + tx * 4 + c) * N + n] = f2bf(acc[r][c]);
    }
    // s1/s2 partials over this block's 64 o's: reduce across the 16 tx lanes
    float p1 = acc[r][0] * a1v.x + acc[r][1] * a1v.y + acc[r][2] * a1v.z + acc[r][3] * a1v.w;
    float p2 = acc[r][0] * a2v.x + acc[r][1] * a2v.y + acc[r][2] * a2v.z + acc[r][3] * a2v.w;
    for (int off = 1; off < 16; off <<= 1) { p1 += __shfl_xor(p1, off); p2 += __shfl_xor(p2, off); }
    if (tx == 0) { atomicAdd(s1 + n, p1); atomicAdd(s2 + n, p2); }
  }
}

// ---------------- K4: scal = 1/denom (f64, from u/v) and smax = max(s2) -------------------
__global__ __launch_bounds__(1024) void k_prep(const double* __restrict__ u,
                                               const double* __restrict__ v,
                                               const float* __restrict__ s2,
                                               double* __restrict__ scal,
                                               float* __restrict__ smaxf) {
  __shared__ double lds[64];
  __shared__ float lf[16];
  int t = threadIdx.x;
  double mnu = 1e300, mxu = -1e300, mnv = 1e300, mxv = -1e300;
#pragma unroll
  for (int k = 0; k < 4; ++k) {
    double uu = u[t + k * 1024], vv = v[t + k * 1024];
    mnu = fmin(mnu, uu); mxu = fmax(mxu, uu);
    mnv = fmin(mnv, vv); mxv = fmax(mxv, vv);
  }
  float4 sv = *(const float4*)(s2 + t * 4);
  float sm = fmaxf(fmaxf(sv.x, sv.y), fmaxf(sv.z, sv.w));
  for (int off = 32; off; off >>= 1) {
    mnu = fmin(mnu, __shfl_down(mnu, off)); mxu = fmax(mxu, __shfl_down(mxu, off));
    mnv = fmin(mnv, __shfl_down(mnv, off)); mxv = fmax(mxv, __shfl_down(mxv, off));
    sm = fmaxf(sm, __shfl_down(sm, off));
  }
  int l = t & 63, w_ = t >> 6;  // 16 waves
  if (l == 0) { lds[w_] = mnu; lds[16 + w_] = mxu; lds[32 + w_] = mnv; lds[48 + w_] = mxv; lf[w_] = sm; }
  __syncthreads();
  if (t == 0) {
    double a = 1e300, b = -1e300, c = 1e300, d = -1e300;
    float s = -1e30f;
    for (int k = 0; k < 16; ++k) {
      a = fmin(a, lds[k]); b = fmax(b, lds[16 + k]);
      c = fmin(c, lds[32 + k]); d = fmax(d, lds[48 + k]);
      s = fmaxf(s, lf[k]);
    }
    scal[0] = 1.0 / fmax(fabs(a + c), b + d);
    smaxf[0] = s;
  }
}

// ---------------- K5: block = one row. dn + km planes + P(bf16) + Z[row] ------------------
__global__ __launch_bounds__(256) void k_dnkm(const int* __restrict__ kmask,
                                              const double* __restrict__ u, const double* __restrict__ v,
                                              const double* __restrict__ scal, const float* __restrict__ lamda,
                                              const float* __restrict__ s1, const float* __restrict__ s2,
                                              const float* __restrict__ smaxf,
                                              float* __restrict__ dn, float* __restrict__ kmout,
                                              unsigned short* __restrict__ P, float* __restrict__ Z) {
  const size_t NN = (size_t)N * N;
  const int* k0 = kmask; const int* k1 = kmask + NN; const int* k2 = kmask + 2 * NN;
  float* km0 = kmout; float* km1 = kmout + NN; float* km2 = kmout + 2 * NN;
  int r = blockIdx.x, t = threadIdx.x;
  double inv = scal[0];
  double lam = (double)lamda[0];
  double ui = u[r];
  float s1r = s1[r];
  float mb = s1r + smaxf[0];
  float mi = mb >= 0.0f ? mb : 0.2f * mb;   // upper bound of masked row max (monotone lrelu)
  float zacc = 0.0f;
#pragma unroll
  for (int k = 0; k < 4; ++k) {
    int j = k * 1024 + t * 4;
    size_t base = (size_t)r * N + j;
    double2 va = *(const double2*)(v + j);
    double2 vb = *(const double2*)(v + j + 2);
    double vv[4] = {va.x, va.y, vb.x, vb.y};
    i32x4 m0 = __builtin_nontemporal_load((const i32x4*)(k0 + base));
    i32x4 m1 = __builtin_nontemporal_load((const i32x4*)(k1 + base));
    i32x4 m2 = __builtin_nontemporal_load((const i32x4*)(k2 + base));
    float4 sv = *(const float4*)(s2 + j);
    f32x4 odn, o0, o1, o2;
    u16x4 pw;
#pragma unroll
    for (int c = 0; c < 4; ++c) {
      double dnv = (ui + vv[c]) * inv;
      bool pos = dnv > lam, neg = dnv < -lam;
      float dnf = (pos || neg) ? 0.0f : (float)dnv;
      int mk0 = m0[c], mk1 = m1[c], mk2 = m2[c];
      int p0 = pos ? mk0 : 0;
      int p1 = pos ? mk1 : 0;
      int n0 = neg ? mk1 : 0;
      int n1 = neg ? mk2 : 0;
      odn[c] = dnf;
      o0[c] = (float)(mk0 - p0 - n0);
      o1[c] = (float)(mk1 + p0 - p1 + n0 - n1);
      o2[c] = (float)(mk2 + p1 + n1);
      // attention P for hop-0
      float e = s1r + (&sv.x)[c];
      e = e >= 0.0f ? e : 0.2f * e;
      float pv = mk0 > 0 ? __expf(e - mi) : 0.0f;
      pw[c] = f2bf(pv);
      zacc += pv;
    }
    __builtin_nontemporal_store(odn, (f32x4*)(dn + base));
    __builtin_nontemporal_store(o0, (f32x4*)(km0 + base));
    __builtin_nontemporal_store(o1, (f32x4*)(km1 + base));
    __builtin_nontemporal_store(o2, (f32x4*)(km2 + base));
    *(u16x4*)(P + base) = pw;
  }
  // block-level Z reduce
  __shared__ float lf[4];
  for (int off = 32; off; off >>= 1) zacc += __shfl_down(zacc, off);
  int l = t & 63, w_ = t >> 6;
  if (l == 0) lf[w_] = zacc;
  __syncthreads();
  if (t == 0) Z[r] = lf[0] + lf[1] + lf[2] + lf[3];
}

// ---------------- K6: pure bf16 GEMM Opart[sp] = P[:, sp-chunk] @ Wh0^T chunk -------------
// Grid (N/32, JS), 512 threads = 8 waves. Wave w: rows rbase+(w>>2)*16, o0=(w&3)*64.
__global__ __launch_bounds__(512) void k_attn2(const unsigned short* __restrict__ P,
                                               const unsigned short* __restrict__ Wh0T,
                                               float* __restrict__ Opart) {
  int t = threadIdx.x;
  int w = t >> 6, l = t & 63;
  int o0 = (w & 3) * 64;
  int rbase = blockIdx.x * 32 + (w >> 2) * 16;
  int row = l & 15;
  int kg = l >> 4;
  int irow = rbase + row;
  f32x4 acc0 = {0,0,0,0}, acc1 = {0,0,0,0}, acc2 = {0,0,0,0}, acc3 = {0,0,0,0};
  const unsigned short* abase = P + (size_t)irow * N + 8 * kg;
  const unsigned short* bbase = Wh0T + ((size_t)(o0 + row) * N + 8 * kg);
  int jbeg = blockIdx.y * JCH;
#pragma unroll 4
  for (int j0 = jbeg; j0 < jbeg + JCH; j0 += 32) {
    bf16x8 af = *(const bf16x8*)(abase + j0);
    bf16x8 b0 = *(const bf16x8*)(bbase + j0);
    bf16x8 b1 = *(const bf16x8*)(bbase + 16 * N + j0);
    bf16x8 b2 = *(const bf16x8*)(bbase + 32 * N + j0);
    bf16x8 b3 = *(const bf16x8*)(bbase + 48 * N + j0);
    acc0 = __builtin_amdgcn_mfma_f32_16x16x32_bf16(af, b0, acc0, 0, 0, 0);
    acc1 = __builtin_amdgcn_mfma_f32_16x16x32_bf16(af, b1, acc1, 0, 0, 0);
    acc2 = __builtin_amdgcn_mfma_f32_16x16x32_bf16(af, b2, acc2, 0, 0, 0);
    acc3 = __builtin_amdgcn_mfma_f32_16x16x32_bf16(af, b3, acc3, 0, 0, 0);
  }
  float* op = Opart + (size_t)blockIdx.y * N * DOUT;
  int col = l & 15, rw = (l >> 4) * 4;
  f32x4 accs[4] = {acc0, acc1, acc2, acc3};
#pragma unroll
  for (int reg = 0; reg < 4; ++reg) {
    int i = rbase + rw + reg;
#pragma unroll
    for (int os = 0; os < 4; ++os) {
      op[(size_t)i * DOUT + o0 + os * 16 + col] = accs[os][reg];
    }
  }
}

// ---------------- K7: reduce JS partials, normalize by Z, skip term, ELU ------------------
__global__ __launch_bounds__(256) void k_ored(const float* __restrict__ Opart,
                                              const float* __restrict__ Z,
                                              const float* __restrict__ Wh0,
                                              float* __restrict__ out) {
  int i = blockIdx.x, t = threadIdx.x;
  size_t idx = (size_t)i * DOUT + t;
  float s = 0.0f;
#pragma unroll
  for (int sp = 0; sp < JS; ++sp) s += Opart[(size_t)sp * N * DOUT + idx];
  float val = 0.9f * (s / Z[i]) + 0.1f * Wh0[idx];
  out[idx] = val > 0.0f ? val : expm1f(val);
}

extern "C" void kernel_launch(void* const* d_in, const int* in_sizes, int n_in,
                              void* d_out, int out_size, void* d_ws, size_t ws_size,
                              hipStream_t stream) {
  const float* h     = (const float*)d_in[0];
  const float* W     = (const float*)d_in[1];
  const float* a     = (const float*)d_in[2];
  const float* disc  = (const float*)d_in[3];
  const int*   kmask = (const int*)d_in[4];
  const float* lamda = (const float*)d_in[5];

  float* out = (float*)d_out;                    // [N, DOUT]
  float* dn  = out + (size_t)N * DOUT;           // [N, N]
  float* km  = dn + (size_t)N * N;               // [3, N, N]

  char* ws = (char*)d_ws;
  double* p    = (double*)ws;                          // 4KB
  double* q    = (double*)(ws + 4096);                 // 4KB
  double* u    = (double*)(ws + 8192);                 // 32KB
  double* v    = (double*)(ws + 8192 + 32768);         // 32KB
  double* scal = (double*)(ws + 8192 + 65536);         // 8B
  float* smaxf = (float*)(ws + 8192 + 65536 + 64);     // 4B (pad to 256)
  char* ws2 = ws + 8192 + 65536 + 256;
  float* s1 = (float*)ws2;                             // 16KB
  float* s2 = (float*)(ws2 + 16384);                   // 16KB
  float* Z  = (float*)(ws2 + 32768);                   // 16KB
  char* ws3 = ws2 + 49152;
  float* Wh0           = (float*)ws3;                                    // 4MB
  unsigned short* Wh0T = (unsigned short*)(ws3 + (size_t)N * DOUT * 4);  // 2MB
  unsigned short* P    = (unsigned short*)(ws3 + (size_t)N * DOUT * 6);  // 32MB
  float* Opart         = (float*)(ws3 + (size_t)N * DOUT * 6 + (size_t)N * N * 2);  // 32MB

  k_pq<<<DIN, 256, 0, stream>>>(W, disc, p, q, s1, s2);
  k_uv<<<N, 256, 0, stream>>>(h, p, q, u, v);
  k_wh0<<<dim3(N / 32, DOUT / 64), 256, 0, stream>>>(h, W, a, Wh0, Wh0T, s1, s2);
  k_prep<<<1, 1024, 0, stream>>>(u, v, s2, scal, smaxf);
  k_dnkm<<<N, 256, 0, stream>>>(kmask, u, v, scal, lamda, s1, s2, smaxf, dn, km, P, Z);
  k_attn2<<<dim3(N / 32, JS), 512, 0, stream>>>(P, Wh0T, Opart);
  k_ored<<<N, 256, 0, stream>>>(Opart, Z, Wh0, out);
}

// Round 6
// 527.561 us; speedup vs baseline: 1.1778x; 1.0228x over previous
//
#include <hip/hip_runtime.h>
#include <hip/hip_bf16.h>
#include <math.h>

#define N 4096
#define DIN 512
#define DOUT 256
#define JS 8          // j-splits for the attention GEMM
#define JCH (N / JS)  // 512 j per split

typedef short bf16x8 __attribute__((ext_vector_type(8)));
typedef float f32x4 __attribute__((ext_vector_type(4)));
typedef int i32x4 __attribute__((ext_vector_type(4)));
typedef unsigned short u16x4 __attribute__((ext_vector_type(4)));

static __device__ __forceinline__ unsigned short f2bf(float x) {
  __hip_bfloat16 b = __float2bfloat16(x);
  return __builtin_bit_cast(unsigned short, b);
}
static __device__ __forceinline__ float bf2f(unsigned short x) {
  unsigned int u = ((unsigned int)x) << 16;
  return __uint_as_float(u);
}

// ---------------- K1: p[i], q[i] (f64 rank-1 collapse of dischange); zero s1/s2 ----------
__global__ __launch_bounds__(256) void k_pq(const float* __restrict__ W,
                                            const float* __restrict__ disc,
                                            double* __restrict__ p, double* __restrict__ q,
                                            float* __restrict__ s1, float* __restrict__ s2) {
  int i = blockIdx.x;   // 0..511
  int t = threadIdx.x;  // 0..255 = o
  if (i < 16) s1[i * 256 + t] = 0.0f;
  else if (i < 32) s2[(i - 16) * 256 + t] = 0.0f;
  __shared__ double lds[8];
  double accp = 0.0, accq = 0.0;
  const double wts[3] = {1.0, 0.5, 0.25};
#pragma unroll
  for (int k = 0; k < 3; ++k) {
    double w = (double)W[((size_t)(k * DIN + i)) * DOUT + t];
    accp += wts[k] * w * (double)disc[t];
    accq += wts[k] * w * (double)disc[DOUT + t];
  }
  for (int off = 32; off; off >>= 1) { accp += __shfl_down(accp, off); accq += __shfl_down(accq, off); }
  int l = t & 63, w_ = t >> 6;
  if (l == 0) { lds[w_] = accp; lds[4 + w_] = accq; }
  __syncthreads();
  if (t == 0) {
    p[i] = lds[0] + lds[1] + lds[2] + lds[3];
    q[i] = lds[4] + lds[5] + lds[6] + lds[7];
  }
}

// ---------------- K2: u[n] = h[n,:]·p, v[n] = h[n,:]·q (f64) ------------------------------
__global__ __launch_bounds__(256) void k_uv(const float* __restrict__ h,
                                            const double* __restrict__ p, const double* __restrict__ q,
                                            double* __restrict__ u, double* __restrict__ v) {
  __shared__ double lds[8];
  int n = blockIdx.x, t = threadIdx.x;
  double su = 0.0, sv = 0.0;
#pragma unroll
  for (int i = t; i < DIN; i += 256) {
    double hv = (double)h[(size_t)n * DIN + i];
    su += hv * p[i];
    sv += hv * q[i];
  }
  for (int off = 32; off; off >>= 1) { su += __shfl_down(su, off); sv += __shfl_down(sv, off); }
  int l = t & 63, w_ = t >> 6;
  if (l == 0) { lds[w_] = su; lds[4 + w_] = sv; }
  __syncthreads();
  if (t == 0) {
    u[n] = lds[0] + lds[1] + lds[2] + lds[3];
    v[n] = lds[4] + lds[5] + lds[6] + lds[7];
  }
}

// ---------------- K3: Wh0 = h @ W0 (f32) + Wh0T bf16 + s1/s2 atomic partials --------------
__global__ __launch_bounds__(256) void k_wh0(const float* __restrict__ h, const float* __restrict__ W,
                                             const float* __restrict__ a,
                                             float* __restrict__ Wh0, unsigned short* __restrict__ Wh0T,
                                             float* __restrict__ s1, float* __restrict__ s2) {
  __shared__ float As[32][20];  // [m][k]
  __shared__ float Bs[16][72];  // [k][n]
  int t = threadIdx.x;
  int i0 = blockIdx.x * 32, o0 = blockIdx.y * 64;
  int tx = t & 15, ty = t >> 4;
  float acc[2][4] = {};
  int am = t >> 2, ak = (t & 3) * 4;   // A staging (t<128)
  int bk = t >> 4, bn = (t & 15) * 4;  // B staging
  float4 pa, pb;
  if (t < 128) pa = *(const float4*)(h + (size_t)(i0 + am) * DIN + ak);
  pb = *(const float4*)(W + (size_t)bk * DOUT + o0 + bn);
  for (int kb = 0; kb < DIN; kb += 16) {
    if (t < 128) *(float4*)&As[am][ak] = pa;
    *(float4*)&Bs[bk][bn] = pb;
    __syncthreads();
    if (kb + 16 < DIN) {
      if (t < 128) pa = *(const float4*)(h + (size_t)(i0 + am) * DIN + kb + 16 + ak);
      pb = *(const float4*)(W + (size_t)(kb + 16 + bk) * DOUT + o0 + bn);
    }
#pragma unroll
    for (int kk = 0; kk < 16; ++kk) {
      float a0 = As[ty * 2 + 0][kk], a1 = As[ty * 2 + 1][kk];
      float4 b = *(const float4*)&Bs[kk][tx * 4];
      acc[0][0] += a0 * b.x; acc[0][1] += a0 * b.y; acc[0][2] += a0 * b.z; acc[0][3] += a0 * b.w;
      acc[1][0] += a1 * b.x; acc[1][1] += a1 * b.y; acc[1][2] += a1 * b.z; acc[1][3] += a1 * b.w;
    }
    __syncthreads();
  }
  float4 a1v = *(const float4*)(a + o0 + tx * 4);
  float4 a2v = *(const float4*)(a + DOUT + o0 + tx * 4);
#pragma unroll
  for (int r = 0; r < 2; ++r) {
    int n = i0 + ty * 2 + r;
    float4 vo = {acc[r][0], acc[r][1], acc[r][2], acc[r][3]};
    *(float4*)(Wh0 + (size_t)n * DOUT + o0 + tx * 4) = vo;
#pragma unroll
    for (int c = 0; c < 4; ++c) {
      Wh0T[(size_t)(o0 + tx * 4 + c) * N + n] = f2bf(acc[r][c]);
    }
    // s1/s2 partials over this block's 64 o's: reduce across the 16 tx lanes
    float p1 = acc[r][0] * a1v.x + acc[r][1] * a1v.y + acc[r][2] * a1v.z + acc[r][3] * a1v.w;
    float p2 = acc[r][0] * a2v.x + acc[r][1] * a2v.y + acc[r][2] * a2v.z + acc[r][3] * a2v.w;
    for (int off = 1; off < 16; off <<= 1) { p1 += __shfl_xor(p1, off); p2 += __shfl_xor(p2, off); }
    if (tx == 0) { atomicAdd(s1 + n, p1); atomicAdd(s2 + n, p2); }
  }
}

// ---------------- K4: scal = 1/denom (f64, from u/v) and smax = max(s2) -------------------
__global__ __launch_bounds__(1024) void k_prep(const double* __restrict__ u,
                                               const double* __restrict__ v,
                                               const float* __restrict__ s2,
                                               double* __restrict__ scal,
                                               float* __restrict__ smaxf) {
  __shared__ double lds[64];
  __shared__ float lf[16];
  int t = threadIdx.x;
  double mnu = 1e300, mxu = -1e300, mnv = 1e300, mxv = -1e300;
#pragma unroll
  for (int k = 0; k < 4; ++k) {
    double uu = u[t + k * 1024], vv = v[t + k * 1024];
    mnu = fmin(mnu, uu); mxu = fmax(mxu, uu);
    mnv = fmin(mnv, vv); mxv = fmax(mxv, vv);
  }
  float4 sv = *(const float4*)(s2 + t * 4);
  float sm = fmaxf(fmaxf(sv.x, sv.y), fmaxf(sv.z, sv.w));
  for (int off = 32; off; off >>= 1) {
    mnu = fmin(mnu, __shfl_down(mnu, off)); mxu = fmax(mxu, __shfl_down(mxu, off));
    mnv = fmin(mnv, __shfl_down(mnv, off)); mxv = fmax(mxv, __shfl_down(mxv, off));
    sm = fmaxf(sm, __shfl_down(sm, off));
  }
  int l = t & 63, w_ = t >> 6;  // 16 waves
  if (l == 0) { lds[w_] = mnu; lds[16 + w_] = mxu; lds[32 + w_] = mnv; lds[48 + w_] = mxv; lf[w_] = sm; }
  __syncthreads();
  if (t == 0) {
    double a = 1e300, b = -1e300, c = 1e300, d = -1e300;
    float s = -1e30f;
    for (int k = 0; k < 16; ++k) {
      a = fmin(a, lds[k]); b = fmax(b, lds[16 + k]);
      c = fmin(c, lds[32 + k]); d = fmax(d, lds[48 + k]);
      s = fmaxf(s, lf[k]);
    }
    scal[0] = 1.0 / fmax(fabs(a + c), b + d);
    smaxf[0] = s;
  }
}

// ---------------- K5: block = one row. dn + km planes + P(bf16) + Z[row] ------------------
__global__ __launch_bounds__(256) void k_dnkm(const int* __restrict__ kmask,
                                              const double* __restrict__ u, const double* __restrict__ v,
                                              const double* __restrict__ scal, const float* __restrict__ lamda,
                                              const float* __restrict__ s1, const float* __restrict__ s2,
                                              const float* __restrict__ smaxf,
                                              float* __restrict__ dn, float* __restrict__ kmout,
                                              unsigned short* __restrict__ P, float* __restrict__ Z) {
  const size_t NN = (size_t)N * N;
  const int* k0 = kmask; const int* k1 = kmask + NN; const int* k2 = kmask + 2 * NN;
  float* km0 = kmout; float* km1 = kmout + NN; float* km2 = kmout + 2 * NN;
  int r = blockIdx.x, t = threadIdx.x;
  double inv = scal[0];
  double lam = (double)lamda[0];
  double ui = u[r];
  float s1r = s1[r];
  float mb = s1r + smaxf[0];
  float mi = mb >= 0.0f ? mb : 0.2f * mb;   // upper bound of masked row max (monotone lrelu)
  float zacc = 0.0f;
#pragma unroll
  for (int k = 0; k < 4; ++k) {
    int j = k * 1024 + t * 4;
    size_t base = (size_t)r * N + j;
    double2 va = *(const double2*)(v + j);
    double2 vb = *(const double2*)(v + j + 2);
    double vv[4] = {va.x, va.y, vb.x, vb.y};
    i32x4 m0 = __builtin_nontemporal_load((const i32x4*)(k0 + base));
    i32x4 m1 = __builtin_nontemporal_load((const i32x4*)(k1 + base));
    i32x4 m2 = __builtin_nontemporal_load((const i32x4*)(k2 + base));
    float4 sv = *(const float4*)(s2 + j);
    f32x4 odn, o0, o1, o2;
    u16x4 pw;
#pragma unroll
    for (int c = 0; c < 4; ++c) {
      double dnv = (ui + vv[c]) * inv;
      bool pos = dnv > lam, neg = dnv < -lam;
      float dnf = (pos || neg) ? 0.0f : (float)dnv;
      int mk0 = m0[c], mk1 = m1[c], mk2 = m2[c];
      int p0 = pos ? mk0 : 0;
      int p1 = pos ? mk1 : 0;
      int n0 = neg ? mk1 : 0;
      int n1 = neg ? mk2 : 0;
      odn[c] = dnf;
      o0[c] = (float)(mk0 - p0 - n0);
      o1[c] = (float)(mk1 + p0 - p1 + n0 - n1);
      o2[c] = (float)(mk2 + p1 + n1);
      // attention P for hop-0
      float e = s1r + (&sv.x)[c];
      e = e >= 0.0f ? e : 0.2f * e;
      float pv = mk0 > 0 ? __expf(e - mi) : 0.0f;
      pw[c] = f2bf(pv);
      zacc += pv;
    }
    __builtin_nontemporal_store(odn, (f32x4*)(dn + base));
    __builtin_nontemporal_store(o0, (f32x4*)(km0 + base));
    __builtin_nontemporal_store(o1, (f32x4*)(km1 + base));
    __builtin_nontemporal_store(o2, (f32x4*)(km2 + base));
    *(u16x4*)(P + base) = pw;
  }
  // block-level Z reduce
  __shared__ float lf[4];
  for (int off = 32; off; off >>= 1) zacc += __shfl_down(zacc, off);
  int l = t & 63, w_ = t >> 6;
  if (l == 0) lf[w_] = zacc;
  __syncthreads();
  if (t == 0) Z[r] = lf[0] + lf[1] + lf[2] + lf[3];
}

// ---------------- K6: pure bf16 GEMM Opart[sp] = P[:, sp-chunk] @ Wh0^T chunk -------------
// Grid (N/64, JS), 512 threads = 8 waves. Wave w: row-tile rt=w>>1 (16 rows), o-half oh=w&1 (128 o).
__global__ __launch_bounds__(512) void k_attn2(const unsigned short* __restrict__ P,
                                               const unsigned short* __restrict__ Wh0T,
                                               unsigned short* __restrict__ Opart) {
  int t = threadIdx.x;
  int w = t >> 6, l = t & 63;
  int o0 = (w & 1) * 128;
  int rbase = blockIdx.x * 64 + (w >> 1) * 16;
  int row = l & 15;
  int kg = l >> 4;
  int irow = rbase + row;
  f32x4 acc[8] = {};
  const unsigned short* abase = P + (size_t)irow * N + 8 * kg;
  const unsigned short* bbase = Wh0T + ((size_t)(o0 + row) * N + 8 * kg);
  int jbeg = blockIdx.y * JCH;
#pragma unroll 2
  for (int j0 = jbeg; j0 < jbeg + JCH; j0 += 32) {
    bf16x8 af = *(const bf16x8*)(abase + j0);
#pragma unroll
    for (int os = 0; os < 8; ++os) {
      bf16x8 b = *(const bf16x8*)(bbase + (size_t)os * 16 * N + j0);
      acc[os] = __builtin_amdgcn_mfma_f32_16x16x32_bf16(af, b, acc[os], 0, 0, 0);
    }
  }
  unsigned short* op = Opart + (size_t)blockIdx.y * N * DOUT;
  int col = l & 15, rw = (l >> 4) * 4;
#pragma unroll
  for (int reg = 0; reg < 4; ++reg) {
    int i = rbase + rw + reg;
#pragma unroll
    for (int os = 0; os < 8; ++os) {
      op[(size_t)i * DOUT + o0 + os * 16 + col] = f2bf(acc[os][reg]);
    }
  }
}

// ---------------- K7: reduce JS bf16 partials, normalize by Z, skip term, ELU -------------
__global__ __launch_bounds__(256) void k_ored(const unsigned short* __restrict__ Opart,
                                              const float* __restrict__ Z,
                                              const float* __restrict__ Wh0,
                                              float* __restrict__ out) {
  int i = blockIdx.x, t = threadIdx.x;
  size_t idx = (size_t)i * DOUT + t;
  float s = 0.0f;
#pragma unroll
  for (int sp = 0; sp < JS; ++sp) s += bf2f(Opart[(size_t)sp * N * DOUT + idx]);
  float val = 0.9f * (s / Z[i]) + 0.1f * Wh0[idx];
  out[idx] = val > 0.0f ? val : expm1f(val);
}

extern "C" void kernel_launch(void* const* d_in, const int* in_sizes, int n_in,
                              void* d_out, int out_size, void* d_ws, size_t ws_size,
                              hipStream_t stream) {
  const float* h     = (const float*)d_in[0];
  const float* W     = (const float*)d_in[1];
  const float* a     = (const float*)d_in[2];
  const float* disc  = (const float*)d_in[3];
  const int*   kmask = (const int*)d_in[4];
  const float* lamda = (const float*)d_in[5];

  float* out = (float*)d_out;                    // [N, DOUT]
  float* dn  = out + (size_t)N * DOUT;           // [N, N]
  float* km  = dn + (size_t)N * N;               // [3, N, N]

  char* ws = (char*)d_ws;
  double* p    = (double*)ws;                          // 4KB
  double* q    = (double*)(ws + 4096);                 // 4KB
  double* u    = (double*)(ws + 8192);                 // 32KB
  double* v    = (double*)(ws + 8192 + 32768);         // 32KB
  double* scal = (double*)(ws + 8192 + 65536);         // 8B
  float* smaxf = (float*)(ws + 8192 + 65536 + 64);     // 4B (pad to 256)
  char* ws2 = ws + 8192 + 65536 + 256;
  float* s1 = (float*)ws2;                             // 16KB
  float* s2 = (float*)(ws2 + 16384);                   // 16KB
  float* Z  = (float*)(ws2 + 32768);                   // 16KB
  char* ws3 = ws2 + 49152;
  float* Wh0           = (float*)ws3;                                    // 4MB
  unsigned short* Wh0T = (unsigned short*)(ws3 + (size_t)N * DOUT * 4);  // 2MB
  unsigned short* P    = (unsigned short*)(ws3 + (size_t)N * DOUT * 6);  // 32MB
  unsigned short* Opart = (unsigned short*)(ws3 + (size_t)N * DOUT * 6 + (size_t)N * N * 2);  // 16MB

  k_pq<<<DIN, 256, 0, stream>>>(W, disc, p, q, s1, s2);
  k_uv<<<N, 256, 0, stream>>>(h, p, q, u, v);
  k_wh0<<<dim3(N / 32, DOUT / 64), 256, 0, stream>>>(h, W, a, Wh0, Wh0T, s1, s2);
  k_prep<<<1, 1024, 0, stream>>>(u, v, s2, scal, smaxf);
  k_dnkm<<<N, 256, 0, stream>>>(kmask, u, v, scal, lamda, s1, s2, smaxf, dn, km, P, Z);
  k_attn2<<<dim3(N / 64, JS), 512, 0, stream>>>(P, Wh0T, Opart);
  k_ored<<<N, 256, 0, stream>>>(Opart, Z, Wh0, out);
}